// Round 3
// baseline (570.013 us; speedup 1.0000x reference)
//
#include <hip/hip_runtime.h>
#include <hip/hip_bf16.h>
#include <cstdint>
#include <cstddef>

#define B_DIM 8
#define L_DIM 4096
#define D_INN 1024
#define H_DIM 1024
#define LATENTD 256
#define SEGLEN 128
#define KSUB 32
#define M_HALF (B_DIM * L_DIM)      // 32768
#define M_TOTAL (2 * M_HALF)        // 65536

typedef __attribute__((ext_vector_type(8))) short bf16x8;
typedef __attribute__((ext_vector_type(4))) float f32x4;

static __device__ __forceinline__ unsigned short f2bf(float x) {
  __hip_bfloat16 b = __float2bfloat16(x);
  return __builtin_bit_cast(unsigned short, b);
}

// pack hi16(lo),hi16(hi) -> one u32 (bf16 truncation; 1 v_perm_b32)
static __device__ __forceinline__ unsigned int pack_trunc(float lo, float hi) {
  return __builtin_amdgcn_perm(__builtin_bit_cast(unsigned int, hi),
                               __builtin_bit_cast(unsigned int, lo),
                               0x07060302u);
}

static __device__ __forceinline__ void async16(const unsigned short* g, unsigned short* l) {
  __builtin_amdgcn_global_load_lds(
      (const __attribute__((address_space(1))) unsigned int*)g,
      (__attribute__((address_space(3))) unsigned int*)l,
      16, 0, 0);
}

// ---------------- prep kernels ----------------

__global__ __launch_bounds__(256) void decay_kernel(const float* __restrict__ a_raw,
                                                    float* __restrict__ avec,
                                                    float* __restrict__ gvec,
                                                    float* __restrict__ a128v) {
  int h = blockIdx.x * 256 + threadIdx.x;
  if (h >= H_DIM) return;
  float a = 1.f / (1.f + expf(-a_raw[h]));
  float p = 1.f, g = 0.f;
  for (int j = 0; j < SEGLEN; j++) { g += p; p *= a; }
  avec[h] = a; gvec[h] = g; a128v[h] = p;   // p = a^128
}

__global__ __launch_bounds__(256) void wproj_transpose_kernel(const float* __restrict__ W,
                                                              unsigned short* __restrict__ WT) {
  __shared__ float tile[64][65];
  int d0 = blockIdx.x * 64, h0 = blockIdx.y * 64;
  for (int i = threadIdx.x; i < 64 * 64; i += 256) {
    int dd = i >> 6, hh = i & 63;
    tile[dd][hh] = W[(size_t)(d0 + dd) * H_DIM + h0 + hh];
  }
  __syncthreads();
  for (int i = threadIdx.x; i < 64 * 64; i += 256) {
    int hh = i >> 6, dd = i & 63;
    WT[(size_t)(h0 + hh) * D_INN + d0 + dd] = f2bf(tile[dd][hh]);
  }
}

// transpose-convert W_out -> WoutT (1024x1024), W_mu/W_lv -> WcatT (512x1024)
__global__ __launch_bounds__(256) void prep2_kernel(const float* __restrict__ Wo,
                                                    const float* __restrict__ Wm,
                                                    const float* __restrict__ Wl,
                                                    unsigned short* __restrict__ WoutT,
                                                    unsigned short* __restrict__ WcatT) {
  __shared__ float tile[64][65];
  int z = blockIdx.z;
  const float* src; unsigned short* dst; int N; int rowoff;
  if (z == 0)      { src = Wo; dst = WoutT; N = 1024; rowoff = 0; }
  else if (z == 1) { src = Wm; dst = WcatT; N = 256;  rowoff = 0; }
  else             { src = Wl; dst = WcatT; N = 256;  rowoff = 256; }
  int k0 = blockIdx.x * 64, n0 = blockIdx.y * 64;
  if (n0 >= N) return;
  for (int i = threadIdx.x; i < 64 * 64; i += 256) {
    int kk = i >> 6, nn = i & 63;
    tile[kk][nn] = src[(size_t)(k0 + kk) * N + n0 + nn];
  }
  __syncthreads();
  for (int i = threadIdx.x; i < 64 * 64; i += 256) {
    int nn = i >> 6, kk = i & 63;
    dst[(size_t)(rowoff + n0 + nn) * 1024 + k0 + kk] = f2bf(tile[kk][nn]);
  }
}

// ---------------- main GEMM + segment decay reduction (reads fp32 A directly) ----
// Dred[bm*1024+h] = sum_j a^(127-j) * (A_row(bm*128+j) . W[:,h]) + b[h]*g[h]
// A rows [0,32768) = targets, [32768,65536) = decoder (virtual stacking, no copy).
// XCD swizzle: idx = 64*m + 8*bn + c -> bm = 8*m + c. Under round-robin
// dispatch (XCD = idx%8 = c) all 8 bn-siblings of a bm land on ONE XCD, so
// the fp32 A tile (256 KB) is fetched into that L2 once.

__global__ __launch_bounds__(256) void gemm_seg_kernel(const float* __restrict__ Tgt,
                                                       const float* __restrict__ Dec,
                                                       const unsigned short* __restrict__ WT,
                                                       const float* __restrict__ avec,
                                                       const float* __restrict__ gvec,
                                                       const float* __restrict__ bproj,
                                                       float* __restrict__ Dred) {
  __shared__ alignas(16) unsigned short As[128 * 32];
  __shared__ alignas(16) unsigned short Bs[128 * 32];
  __shared__ float aLds[128];
  __shared__ float redLds[2][128];

  const int t = threadIdx.x;
  const int lane = t & 63;
  const int wave = t >> 6;
  const int idx = blockIdx.x;
  const int cxd = idx & 7;
  const int bn = (idx >> 3) & 7;
  const int bm = ((idx >> 6) << 3) + cxd;   // 0..511
  const int lo = lane & 15;
  const int q = lane >> 4;
  const int wm = wave & 1;
  const int wn = wave >> 1;

  if (t < 128) aLds[t] = avec[bn * 128 + t];

  f32x4 acc[4][4];
#pragma unroll
  for (int i = 0; i < 4; i++)
#pragma unroll
    for (int j = 0; j < 4; j++) acc[i][j] = (f32x4){0.f, 0.f, 0.f, 0.f};

  const int r0 = t >> 2;          // 0..63
  const int c0 = (t & 3) * 8;     // 0,8,16,24
  const float* Asrc = (bm < 256)
      ? (Tgt + (size_t)bm * 128 * D_INN)
      : (Dec + (size_t)(bm - 256) * 128 * D_INN);
  const float* Ag0 = Asrc + (size_t)r0 * D_INN + c0;
  const float* Ag1 = Asrc + (size_t)(64 + r0) * D_INN + c0;
  const unsigned short* Bg0 = WT + ((size_t)bn * 128 + r0) * D_INN + c0;
  const unsigned short* Bg1 = WT + ((size_t)bn * 128 + 64 + r0) * D_INN + c0;
  unsigned short* Al0 = &As[t * 8];
  unsigned short* Al1 = &As[(256 + t) * 8];
  unsigned short* Bl0 = &Bs[t * 8];
  unsigned short* Bl1 = &Bs[(256 + t) * 8];

  // register prefetch pipeline for fp32 A: cur = iter kk, nxt loads during MFMA
  float4 cur0a = *(const float4*)(Ag0);
  float4 cur0b = *(const float4*)(Ag0 + 4);
  float4 cur1a = *(const float4*)(Ag1);
  float4 cur1b = *(const float4*)(Ag1 + 4);

  for (int kk = 0; kk < D_INN; kk += 32) {
    async16(Bg0 + kk, Bl0);
    async16(Bg1 + kk, Bl1);
    {
      uint4 u0, u1;
      u0.x = pack_trunc(cur0a.x, cur0a.y); u0.y = pack_trunc(cur0a.z, cur0a.w);
      u0.z = pack_trunc(cur0b.x, cur0b.y); u0.w = pack_trunc(cur0b.z, cur0b.w);
      u1.x = pack_trunc(cur1a.x, cur1a.y); u1.y = pack_trunc(cur1a.z, cur1a.w);
      u1.z = pack_trunc(cur1b.x, cur1b.y); u1.w = pack_trunc(cur1b.z, cur1b.w);
      *(uint4*)Al0 = u0;
      *(uint4*)Al1 = u1;
    }
    __syncthreads();
    if (kk + 32 < D_INN) {
      cur0a = *(const float4*)(Ag0 + kk + 32);
      cur0b = *(const float4*)(Ag0 + kk + 36);
      cur1a = *(const float4*)(Ag1 + kk + 32);
      cur1b = *(const float4*)(Ag1 + kk + 36);
    }
    bf16x8 af[4], bv[4];
#pragma unroll
    for (int i = 0; i < 4; i++)
      af[i] = *(const bf16x8*)&As[(wm * 64 + i * 16 + lo) * 32 + q * 8];
#pragma unroll
    for (int j = 0; j < 4; j++)
      bv[j] = *(const bf16x8*)&Bs[(wn * 64 + j * 16 + lo) * 32 + q * 8];
#pragma unroll
    for (int i = 0; i < 4; i++)
#pragma unroll
      for (int j = 0; j < 4; j++)
        acc[i][j] = __builtin_amdgcn_mfma_f32_16x16x32_bf16(af[i], bv[j], acc[i][j], 0, 0, 0);
    __syncthreads();
  }

  // Epilogue: column-wise Horner reduction, weight a^(63-row) per 64-row half.
  float D64[4];
#pragma unroll
  for (int j = 0; j < 4; j++) {
    const int col = wn * 64 + j * 16 + lo;
    const float a = aLds[col];
    const float a2 = a * a, a4 = a2 * a2, a8 = a4 * a4, a16 = a8 * a8;
    float P = 0.f;
#pragma unroll
    for (int i = 0; i < 4; i++) {
      f32x4 u = acc[i][j];
      float vi = ((u.x * a + u.y) * a + u.z) * a + u.w;
      P = P * a16 + vi;
    }
    const float qf = (q == 3) ? 1.f : ((q == 2) ? a4 : ((q == 1) ? a4 * a4 : a4 * a4 * a4));
    P *= qf;
    P += __shfl_xor(P, 16);
    P += __shfl_xor(P, 32);
    D64[j] = P;
  }
  if (q == 0) {
#pragma unroll
    for (int j = 0; j < 4; j++) redLds[wm][wn * 64 + j * 16 + lo] = D64[j];
  }
  __syncthreads();
  if (t < 128) {
    const int col = t;
    const int h = bn * 128 + col;
    const float a = aLds[col];
    const float a2 = a * a, a4 = a2 * a2, a8 = a4 * a4, a16 = a8 * a8;
    const float a32 = a16 * a16, a64 = a32 * a32;
    float D = redLds[0][col] * a64 + redLds[1][col];
    D += bproj[h] * gvec[h];           // bias folded: b * sum_{i<128} a^i
    Dred[(size_t)bm * H_DIM + h] = D;
  }
}

// ---------------- prefix scan over k + hT (bf16 out) ----------------
__global__ __launch_bounds__(256) void state_kernel(const float* __restrict__ Dred,
                                                    const float* __restrict__ a128v,
                                                    unsigned short* __restrict__ hTbf) {
  int idx = blockIdx.x * 256 + threadIdx.x;  // b*1024 + h, 8192 total
  int b = idx >> 10, h = idx & 1023;
  const float* S = Dred + (size_t)b * KSUB * H_DIM + h;            // corr stream
  const float* Dd = Dred + (size_t)(B_DIM + b) * KSUB * H_DIM + h; // dec stream
  float A = a128v[h];
  float C = 0.f;
  for (int k = 0; k < KSUB; k++) {
    hTbf[((size_t)(b * KSUB + k)) * H_DIM + h] = f2bf(fmaf(A, C, Dd[(size_t)k * H_DIM]));
    C = fmaf(A, C, S[(size_t)k * H_DIM]);
  }
}

// ---------------- MFMA heads ----------------
// head1: y = silu(hT @ W_out + b_out)   M=256, N=1024, K=1024, out bf16
__global__ __launch_bounds__(256) void head1_kernel(const unsigned short* __restrict__ Abf,
                                                    const unsigned short* __restrict__ Bt,
                                                    const float* __restrict__ bias,
                                                    unsigned short* __restrict__ ybf) {
  __shared__ alignas(16) unsigned short As[128 * 32];
  __shared__ alignas(16) unsigned short Bs[128 * 32];
  const int t = threadIdx.x;
  const int lane = t & 63, wave = t >> 6;
  const int bm = blockIdx.x, bn = blockIdx.y;
  const int lo = lane & 15, q = lane >> 4;
  const int wm = wave & 1, wn = wave >> 1;

  f32x4 acc[4][4];
#pragma unroll
  for (int i = 0; i < 4; i++)
#pragma unroll
    for (int j = 0; j < 4; j++) acc[i][j] = (f32x4){0.f, 0.f, 0.f, 0.f};

  const int r0 = t >> 2;
  const int c0 = (t & 3) * 8;
  const unsigned short* Ag0 = Abf + ((size_t)bm * 128 + r0) * 1024 + c0;
  const unsigned short* Ag1 = Abf + ((size_t)bm * 128 + 64 + r0) * 1024 + c0;
  const unsigned short* Bg0 = Bt + ((size_t)bn * 128 + r0) * 1024 + c0;
  const unsigned short* Bg1 = Bt + ((size_t)bn * 128 + 64 + r0) * 1024 + c0;
  unsigned short* Al0 = &As[t * 8];
  unsigned short* Al1 = &As[(256 + t) * 8];
  unsigned short* Bl0 = &Bs[t * 8];
  unsigned short* Bl1 = &Bs[(256 + t) * 8];

  for (int kk = 0; kk < 1024; kk += 32) {
    async16(Ag0 + kk, Al0);
    async16(Ag1 + kk, Al1);
    async16(Bg0 + kk, Bl0);
    async16(Bg1 + kk, Bl1);
    __syncthreads();
    bf16x8 af[4], bv[4];
#pragma unroll
    for (int i = 0; i < 4; i++)
      af[i] = *(const bf16x8*)&As[(wm * 64 + i * 16 + lo) * 32 + q * 8];
#pragma unroll
    for (int j = 0; j < 4; j++)
      bv[j] = *(const bf16x8*)&Bs[(wn * 64 + j * 16 + lo) * 32 + q * 8];
#pragma unroll
    for (int i = 0; i < 4; i++)
#pragma unroll
      for (int j = 0; j < 4; j++)
        acc[i][j] = __builtin_amdgcn_mfma_f32_16x16x32_bf16(af[i], bv[j], acc[i][j], 0, 0, 0);
    __syncthreads();
  }

#pragma unroll
  for (int j = 0; j < 4; j++) {
    const int col = bn * 128 + wn * 64 + j * 16 + lo;
    const float bb = bias[col];
#pragma unroll
    for (int i = 0; i < 4; i++) {
#pragma unroll
      for (int r = 0; r < 4; r++) {
        const int row = bm * 128 + wm * 64 + i * 16 + q * 4 + r;
        float z = acc[i][j][r] + bb;
        float y = z / (1.f + expf(-z));
        ybf[(size_t)row * 1024 + col] = f2bf(y);
      }
    }
  }
}

// head2: [mu|lv] = y @ [W_mu|W_lv] + [b_mu|b_lv]   M=256, N=512, K=1024, out fp32
__global__ __launch_bounds__(256) void head2_kernel(const unsigned short* __restrict__ Abf,
                                                    const unsigned short* __restrict__ Bt,
                                                    const float* __restrict__ bmu,
                                                    const float* __restrict__ blv,
                                                    float* __restrict__ out) {
  __shared__ alignas(16) unsigned short As[128 * 32];
  __shared__ alignas(16) unsigned short Bs[128 * 32];
  const int t = threadIdx.x;
  const int lane = t & 63, wave = t >> 6;
  const int bm = blockIdx.x, bn = blockIdx.y;   // bn 0..3
  const int lo = lane & 15, q = lane >> 4;
  const int wm = wave & 1, wn = wave >> 1;

  f32x4 acc[4][4];
#pragma unroll
  for (int i = 0; i < 4; i++)
#pragma unroll
    for (int j = 0; j < 4; j++) acc[i][j] = (f32x4){0.f, 0.f, 0.f, 0.f};

  const int r0 = t >> 2;
  const int c0 = (t & 3) * 8;
  const unsigned short* Ag0 = Abf + ((size_t)bm * 128 + r0) * 1024 + c0;
  const unsigned short* Ag1 = Abf + ((size_t)bm * 128 + 64 + r0) * 1024 + c0;
  const unsigned short* Bg0 = Bt + ((size_t)bn * 128 + r0) * 1024 + c0;
  const unsigned short* Bg1 = Bt + ((size_t)bn * 128 + 64 + r0) * 1024 + c0;
  unsigned short* Al0 = &As[t * 8];
  unsigned short* Al1 = &As[(256 + t) * 8];
  unsigned short* Bl0 = &Bs[t * 8];
  unsigned short* Bl1 = &Bs[(256 + t) * 8];

  for (int kk = 0; kk < 1024; kk += 32) {
    async16(Ag0 + kk, Al0);
    async16(Ag1 + kk, Al1);
    async16(Bg0 + kk, Bl0);
    async16(Bg1 + kk, Bl1);
    __syncthreads();
    bf16x8 af[4], bv[4];
#pragma unroll
    for (int i = 0; i < 4; i++)
      af[i] = *(const bf16x8*)&As[(wm * 64 + i * 16 + lo) * 32 + q * 8];
#pragma unroll
    for (int j = 0; j < 4; j++)
      bv[j] = *(const bf16x8*)&Bs[(wn * 64 + j * 16 + lo) * 32 + q * 8];
#pragma unroll
    for (int i = 0; i < 4; i++)
#pragma unroll
      for (int j = 0; j < 4; j++)
        acc[i][j] = __builtin_amdgcn_mfma_f32_16x16x32_bf16(af[i], bv[j], acc[i][j], 0, 0, 0);
    __syncthreads();
  }

#pragma unroll
  for (int j = 0; j < 4; j++) {
    const int col = bn * 128 + wn * 64 + j * 16 + lo;   // 0..511
    const float bb = (col < 256) ? bmu[col] : blv[col - 256];
    float* dst = (col < 256) ? (out + col) : (out + 65536 + (col - 256));
#pragma unroll
    for (int i = 0; i < 4; i++) {
#pragma unroll
      for (int r = 0; r < 4; r++) {
        const int row = bm * 128 + wm * 64 + i * 16 + q * 4 + r;
        dst[(size_t)row * 256] = acc[i][j][r] + bb;
      }
    }
  }
}

// ---------------- launcher ----------------
extern "C" void kernel_launch(void* const* d_in, const int* in_sizes, int n_in,
                              void* d_out, int out_size, void* d_ws, size_t ws_size,
                              hipStream_t stream) {
  const float* decoder = (const float*)d_in[0];
  const float* targets = (const float*)d_in[1];
  const float* W_proj = (const float*)d_in[2];
  const float* b_proj = (const float*)d_in[3];
  const float* a_raw = (const float*)d_in[4];
  const float* W_out = (const float*)d_in[5];
  const float* b_out = (const float*)d_in[6];
  const float* W_mu = (const float*)d_in[7];
  const float* b_mu = (const float*)d_in[8];
  const float* W_lv = (const float*)d_in[9];
  const float* b_lv = (const float*)d_in[10];
  float* out = (float*)d_out;

  // compact workspace (~8.6 MB)
  char* ws = (char*)d_ws;
  unsigned short* WT = (unsigned short*)ws;                       // 2 MB
  unsigned short* WoutT = (unsigned short*)(ws + 2097152);        // 2 MB
  unsigned short* WcatT = (unsigned short*)(ws + 4194304);        // 1 MB
  float* avec = (float*)(ws + 5242880);                           // 4 KB
  float* gvec = (float*)(ws + 5246976);                           // 4 KB
  float* a128v = (float*)(ws + 5251072);                          // 4 KB
  float* DredP = (float*)(ws + 5255168);                          // 2 MB
  unsigned short* hTbf = (unsigned short*)(ws + 7352320);         // 512 KB
  unsigned short* ybf = (unsigned short*)(ws + 7876608);          // 512 KB

  decay_kernel<<<4, 256, 0, stream>>>(a_raw, avec, gvec, a128v);
  wproj_transpose_kernel<<<dim3(16, 16), 256, 0, stream>>>(W_proj, WT);
  gemm_seg_kernel<<<4096, 256, 0, stream>>>(targets, decoder, WT, avec, gvec, b_proj, DredP);
  prep2_kernel<<<dim3(16, 16, 3), 256, 0, stream>>>(W_out, W_mu, W_lv, WoutT, WcatT);
  state_kernel<<<32, 256, 0, stream>>>(DredP, a128v, hTbf);
  head1_kernel<<<dim3(2, 8), 256, 0, stream>>>(hTbf, WoutT, b_out, ybf);
  head2_kernel<<<dim3(2, 4), 256, 0, stream>>>(ybf, WcatT, b_mu, b_lv, out);
}

// Round 4
// 535.727 us; speedup vs baseline: 1.0640x; 1.0640x over previous
//
#include <hip/hip_runtime.h>
#include <hip/hip_bf16.h>
#include <cstdint>
#include <cstddef>

#define B_DIM 8
#define L_DIM 4096
#define D_INN 1024
#define H_DIM 1024
#define LATENTD 256
#define SEGLEN 128
#define KSUB 32

typedef __attribute__((ext_vector_type(8))) short bf16x8;
typedef __attribute__((ext_vector_type(4))) float f32x4;

static __device__ __forceinline__ unsigned short f2bf(float x) {
  __hip_bfloat16 b = __float2bfloat16(x);
  return __builtin_bit_cast(unsigned short, b);
}

// pack bf16(lo),bf16(hi) -> u32 {lo16=hi16(lo), hi16=hi16(hi)} (1 v_perm_b32)
static __device__ __forceinline__ unsigned int pack_trunc(float lo, float hi) {
  return __builtin_amdgcn_perm(__builtin_bit_cast(unsigned int, hi),
                               __builtin_bit_cast(unsigned int, lo),
                               0x07060302u);
}

static __device__ __forceinline__ void async16(const unsigned short* g, unsigned short* l) {
  __builtin_amdgcn_global_load_lds(
      (const __attribute__((address_space(1))) unsigned int*)g,
      (__attribute__((address_space(3))) unsigned int*)l,
      16, 0, 0);
}
static __device__ __forceinline__ void async16f(const float* g, float* l) {
  __builtin_amdgcn_global_load_lds(
      (const __attribute__((address_space(1))) unsigned int*)g,
      (__attribute__((address_space(3))) unsigned int*)l,
      16, 0, 0);
}

// ---------------- merged prep kernel ----------------
// blocks [0,256): transpose-convert W_proj -> WT (1024x1024)
// blocks [256,1024): W_out -> WoutT, W_mu/W_lv -> WcatT
// blocks [1024,1028): decay vectors
__global__ __launch_bounds__(256) void prep_kernel(const float* __restrict__ a_raw,
                                                   const float* __restrict__ Wp,
                                                   const float* __restrict__ Wo,
                                                   const float* __restrict__ Wm,
                                                   const float* __restrict__ Wl,
                                                   float* __restrict__ avec,
                                                   float* __restrict__ gvec,
                                                   float* __restrict__ a128v,
                                                   unsigned short* __restrict__ WT,
                                                   unsigned short* __restrict__ WoutT,
                                                   unsigned short* __restrict__ WcatT) {
  __shared__ float tile[64][65];
  const int id = blockIdx.x;
  const int t = threadIdx.x;
  if (id >= 1024) {
    int h = (id - 1024) * 256 + t;
    if (h < H_DIM) {
      float a = 1.f / (1.f + expf(-a_raw[h]));
      float p = 1.f, g = 0.f;
      for (int j = 0; j < SEGLEN; j++) { g += p; p *= a; }
      avec[h] = a; gvec[h] = g; a128v[h] = p;   // p = a^128
    }
    return;
  }
  const float* src; unsigned short* dst; int N; int rowoff; int k0, n0;
  if (id < 256) {
    src = Wp; dst = WT; N = 1024; rowoff = 0;
    k0 = (id >> 4) * 64; n0 = (id & 15) * 64;
  } else {
    int p = id - 256, z = p >> 8, qq = p & 255;
    if (z == 0)      { src = Wo; dst = WoutT; N = 1024; rowoff = 0; }
    else if (z == 1) { src = Wm; dst = WcatT; N = 256;  rowoff = 0; }
    else             { src = Wl; dst = WcatT; N = 256;  rowoff = 256; }
    k0 = (qq >> 4) * 64; n0 = (qq & 15) * 64;
    if (n0 >= N) return;
  }
  for (int i = t; i < 64 * 64; i += 256) {
    int kk = i >> 6, nn = i & 63;
    tile[kk][nn] = src[(size_t)(k0 + kk) * N + n0 + nn];
  }
  __syncthreads();
  for (int i = t; i < 64 * 64; i += 256) {
    int nn = i >> 6, kk = i & 63;
    dst[(size_t)(rowoff + n0 + nn) * 1024 + k0 + kk] = f2bf(tile[kk][nn]);
  }
}

// ---------------- main GEMM + segment decay reduction ----------------
// A is fp32 (targets/decoder, virtually stacked), staged raw via async16 into
// a 128x32 fp32 LDS tile; fp32->bf16 conversion happens in the frag-read
// phase (v_perm). A tile is XOR-swizzled on the GLOBAL side (async16's LDS
// side must be lane-linear): within a row, global chunk g lands at LDS chunk
// g ^ ((row&3)<<1) -> frag reads see 4-way instead of 16-way bank conflicts.
// XCD swizzle: idx = 64*m + 8*bn + c -> bm = 8*m + c; all 8 bn-siblings of a
// bm land on one XCD so the fp32 A tile is fetched into that L2 once.

__global__ __launch_bounds__(256) void gemm_seg_kernel(const float* __restrict__ Tgt,
                                                       const float* __restrict__ Dec,
                                                       const unsigned short* __restrict__ WT,
                                                       const float* __restrict__ avec,
                                                       const float* __restrict__ gvec,
                                                       const float* __restrict__ bproj,
                                                       float* __restrict__ Dred) {
  __shared__ alignas(16) float Asf[128 * 32];           // 16 KB
  __shared__ alignas(16) unsigned short Bs[128 * 32];   // 8 KB
  __shared__ float aLds[128];
  __shared__ float redLds[2][128];

  const int t = threadIdx.x;
  const int lane = t & 63;
  const int wave = t >> 6;
  const int idx = blockIdx.x;
  const int cxd = idx & 7;
  const int bn = (idx >> 3) & 7;
  const int bm = ((idx >> 6) << 3) + cxd;   // 0..511
  const int lo = lane & 15;
  const int q = lane >> 4;
  const int wm = wave & 1;
  const int wn = wave >> 1;

  if (t < 128) aLds[t] = avec[bn * 128 + t];

  f32x4 acc[4][4];
#pragma unroll
  for (int i = 0; i < 4; i++)
#pragma unroll
    for (int j = 0; j < 4; j++) acc[i][j] = (f32x4){0.f, 0.f, 0.f, 0.f};

  const float* Asrc = (bm < 256)
      ? (Tgt + (size_t)bm * 128 * D_INN)
      : (Dec + (size_t)(bm - 256) * 128 * D_INN);

  // A staging: 1024 chunks of 16B; thread t owns chunks t+256*i
  const float* aG[4];
  float* aL[4];
#pragma unroll
  for (int i = 0; i < 4; i++) {
    int c = t + 256 * i;
    int row = c >> 3;
    int g = (c & 7) ^ ((row & 3) << 1);     // global-side swizzle
    aG[i] = Asrc + (size_t)row * D_INN + g * 4;
    aL[i] = &Asf[c * 4];
  }
  // B staging (bf16, unswizzled, as R2)
  const int r0 = t >> 2;
  const int c0 = (t & 3) * 8;
  const unsigned short* Bg0 = WT + ((size_t)bn * 128 + r0) * D_INN + c0;
  const unsigned short* Bg1 = WT + ((size_t)bn * 128 + 64 + r0) * D_INN + c0;
  unsigned short* Bl0 = &Bs[t * 8];
  unsigned short* Bl1 = &Bs[(256 + t) * 8];

  for (int kk = 0; kk < D_INN; kk += 32) {
    async16f(aG[0] + kk, aL[0]);
    async16f(aG[1] + kk, aL[1]);
    async16f(aG[2] + kk, aL[2]);
    async16f(aG[3] + kk, aL[3]);
    async16(Bg0 + kk, Bl0);
    async16(Bg1 + kk, Bl1);
    __syncthreads();
    bf16x8 bv[4];
#pragma unroll
    for (int j = 0; j < 4; j++)
      bv[j] = *(const bf16x8*)&Bs[(wn * 64 + j * 16 + lo) * 32 + q * 8];
#pragma unroll
    for (int i = 0; i < 4; i++) {
      const int ra = wm * 64 + i * 16 + lo;
      const int s = (ra & 3) << 1;
      const float4* p = (const float4*)&Asf[ra * 32 + (((q << 1) ^ s) << 2)];
      float4 X = p[0], Y = p[1];
      uint4 u;
      u.x = pack_trunc(X.x, X.y); u.y = pack_trunc(X.z, X.w);
      u.z = pack_trunc(Y.x, Y.y); u.w = pack_trunc(Y.z, Y.w);
      bf16x8 af = __builtin_bit_cast(bf16x8, u);
#pragma unroll
      for (int j = 0; j < 4; j++)
        acc[i][j] = __builtin_amdgcn_mfma_f32_16x16x32_bf16(af, bv[j], acc[i][j], 0, 0, 0);
    }
    __syncthreads();
  }

  // Epilogue: column-wise Horner reduction, weight a^(63-row) per 64-row half.
  float D64[4];
#pragma unroll
  for (int j = 0; j < 4; j++) {
    const int col = wn * 64 + j * 16 + lo;
    const float a = aLds[col];
    const float a2 = a * a, a4 = a2 * a2;
    const float a16 = a4 * a4 * a4 * a4;
    float P = 0.f;
#pragma unroll
    for (int i = 0; i < 4; i++) {
      f32x4 u = acc[i][j];
      float vi = ((u.x * a + u.y) * a + u.z) * a + u.w;
      P = P * a16 + vi;
    }
    const float qf = (q == 3) ? 1.f : ((q == 2) ? a4 : ((q == 1) ? a4 * a4 : a4 * a4 * a4));
    P *= qf;
    P += __shfl_xor(P, 16);
    P += __shfl_xor(P, 32);
    D64[j] = P;
  }
  if (q == 0) {
#pragma unroll
    for (int j = 0; j < 4; j++) redLds[wm][wn * 64 + j * 16 + lo] = D64[j];
  }
  __syncthreads();
  if (t < 128) {
    const int col = t;
    const int h = bn * 128 + col;
    const float a = aLds[col];
    const float a2 = a * a, a4 = a2 * a2, a8 = a4 * a4, a16 = a8 * a8;
    const float a32 = a16 * a16, a64 = a32 * a32;
    float D = redLds[0][col] * a64 + redLds[1][col];
    D += bproj[h] * gvec[h];           // bias folded: b * sum_{i<128} a^i
    Dred[(size_t)bm * H_DIM + h] = D;
  }
}

// ---------------- prefix scan over k + hT (bf16 out) ----------------
__global__ __launch_bounds__(256) void state_kernel(const float* __restrict__ Dred,
                                                    const float* __restrict__ a128v,
                                                    unsigned short* __restrict__ hTbf) {
  int idx = blockIdx.x * 256 + threadIdx.x;  // b*1024 + h, 8192 total
  int b = idx >> 10, h = idx & 1023;
  const float* S = Dred + (size_t)b * KSUB * H_DIM + h;            // corr stream
  const float* Dd = Dred + (size_t)(B_DIM + b) * KSUB * H_DIM + h; // dec stream
  float A = a128v[h];
  float C = 0.f;
  for (int k = 0; k < KSUB; k++) {
    hTbf[((size_t)(b * KSUB + k)) * H_DIM + h] = f2bf(fmaf(A, C, Dd[(size_t)k * H_DIM]));
    C = fmaf(A, C, S[(size_t)k * H_DIM]);
  }
}

// ---------------- MFMA heads (BK=64: 16 barrier-iters) ----------------
// head1: y = silu(hT @ W_out + b_out)   M=256, N=1024, K=1024, out bf16
__global__ __launch_bounds__(256) void head1_kernel(const unsigned short* __restrict__ Abf,
                                                    const unsigned short* __restrict__ Bt,
                                                    const float* __restrict__ bias,
                                                    unsigned short* __restrict__ ybf) {
  __shared__ alignas(16) unsigned short As[128 * 64];   // 16 KB
  __shared__ alignas(16) unsigned short Bs[128 * 64];   // 16 KB
  const int t = threadIdx.x;
  const int lane = t & 63, wave = t >> 6;
  const int bm = blockIdx.x, bn = blockIdx.y;
  const int lo = lane & 15, q = lane >> 4;
  const int wm = wave & 1, wn = wave >> 1;

  f32x4 acc[4][4];
#pragma unroll
  for (int i = 0; i < 4; i++)
#pragma unroll
    for (int j = 0; j < 4; j++) acc[i][j] = (f32x4){0.f, 0.f, 0.f, 0.f};

  const unsigned short* Ag[4]; const unsigned short* Bg[4];
  unsigned short *Al[4], *Bl[4];
#pragma unroll
  for (int i = 0; i < 4; i++) {
    int c = t + 256 * i;
    int row = c >> 3, colb = (c & 7) * 8;
    Ag[i] = Abf + ((size_t)bm * 128 + row) * 1024 + colb;
    Bg[i] = Bt + ((size_t)bn * 128 + row) * 1024 + colb;
    Al[i] = &As[c * 8];
    Bl[i] = &Bs[c * 8];
  }

  for (int kk = 0; kk < 1024; kk += 64) {
#pragma unroll
    for (int i = 0; i < 4; i++) { async16(Ag[i] + kk, Al[i]); async16(Bg[i] + kk, Bl[i]); }
    __syncthreads();
#pragma unroll
    for (int h = 0; h < 2; h++) {
      bf16x8 af[4], bv[4];
#pragma unroll
      for (int i = 0; i < 4; i++)
        af[i] = *(const bf16x8*)&As[(wm * 64 + i * 16 + lo) * 64 + h * 32 + q * 8];
#pragma unroll
      for (int j = 0; j < 4; j++)
        bv[j] = *(const bf16x8*)&Bs[(wn * 64 + j * 16 + lo) * 64 + h * 32 + q * 8];
#pragma unroll
      for (int i = 0; i < 4; i++)
#pragma unroll
        for (int j = 0; j < 4; j++)
          acc[i][j] = __builtin_amdgcn_mfma_f32_16x16x32_bf16(af[i], bv[j], acc[i][j], 0, 0, 0);
    }
    __syncthreads();
  }

#pragma unroll
  for (int j = 0; j < 4; j++) {
    const int col = bn * 128 + wn * 64 + j * 16 + lo;
    const float bb = bias[col];
#pragma unroll
    for (int i = 0; i < 4; i++) {
#pragma unroll
      for (int r = 0; r < 4; r++) {
        const int row = bm * 128 + wm * 64 + i * 16 + q * 4 + r;
        float z = acc[i][j][r] + bb;
        float y = z / (1.f + expf(-z));
        ybf[(size_t)row * 1024 + col] = f2bf(y);
      }
    }
  }
}

// head2: [mu|lv] = y @ [W_mu|W_lv] + [b_mu|b_lv]   M=256, N=512, K=1024, out fp32
__global__ __launch_bounds__(256) void head2_kernel(const unsigned short* __restrict__ Abf,
                                                    const unsigned short* __restrict__ Bt,
                                                    const float* __restrict__ bmu,
                                                    const float* __restrict__ blv,
                                                    float* __restrict__ out) {
  __shared__ alignas(16) unsigned short As[128 * 64];
  __shared__ alignas(16) unsigned short Bs[128 * 64];
  const int t = threadIdx.x;
  const int lane = t & 63, wave = t >> 6;
  const int bm = blockIdx.x, bn = blockIdx.y;   // bn 0..3
  const int lo = lane & 15, q = lane >> 4;
  const int wm = wave & 1, wn = wave >> 1;

  f32x4 acc[4][4];
#pragma unroll
  for (int i = 0; i < 4; i++)
#pragma unroll
    for (int j = 0; j < 4; j++) acc[i][j] = (f32x4){0.f, 0.f, 0.f, 0.f};

  const unsigned short* Ag[4]; const unsigned short* Bg[4];
  unsigned short *Al[4], *Bl[4];
#pragma unroll
  for (int i = 0; i < 4; i++) {
    int c = t + 256 * i;
    int row = c >> 3, colb = (c & 7) * 8;
    Ag[i] = Abf + ((size_t)bm * 128 + row) * 1024 + colb;
    Bg[i] = Bt + ((size_t)bn * 128 + row) * 1024 + colb;
    Al[i] = &As[c * 8];
    Bl[i] = &Bs[c * 8];
  }

  for (int kk = 0; kk < 1024; kk += 64) {
#pragma unroll
    for (int i = 0; i < 4; i++) { async16(Ag[i] + kk, Al[i]); async16(Bg[i] + kk, Bl[i]); }
    __syncthreads();
#pragma unroll
    for (int h = 0; h < 2; h++) {
      bf16x8 af[4], bv[4];
#pragma unroll
      for (int i = 0; i < 4; i++)
        af[i] = *(const bf16x8*)&As[(wm * 64 + i * 16 + lo) * 64 + h * 32 + q * 8];
#pragma unroll
      for (int j = 0; j < 4; j++)
        bv[j] = *(const bf16x8*)&Bs[(wn * 64 + j * 16 + lo) * 64 + h * 32 + q * 8];
#pragma unroll
      for (int i = 0; i < 4; i++)
#pragma unroll
        for (int j = 0; j < 4; j++)
          acc[i][j] = __builtin_amdgcn_mfma_f32_16x16x32_bf16(af[i], bv[j], acc[i][j], 0, 0, 0);
    }
    __syncthreads();
  }

#pragma unroll
  for (int j = 0; j < 4; j++) {
    const int col = bn * 128 + wn * 64 + j * 16 + lo;   // 0..511
    const float bb = (col < 256) ? bmu[col] : blv[col - 256];
    float* dst = (col < 256) ? (out + col) : (out + 65536 + (col - 256));
#pragma unroll
    for (int i = 0; i < 4; i++) {
#pragma unroll
      for (int r = 0; r < 4; r++) {
        const int row = bm * 128 + wm * 64 + i * 16 + q * 4 + r;
        dst[(size_t)row * 256] = acc[i][j][r] + bb;
      }
    }
  }
}

// ---------------- launcher ----------------
extern "C" void kernel_launch(void* const* d_in, const int* in_sizes, int n_in,
                              void* d_out, int out_size, void* d_ws, size_t ws_size,
                              hipStream_t stream) {
  const float* decoder = (const float*)d_in[0];
  const float* targets = (const float*)d_in[1];
  const float* W_proj = (const float*)d_in[2];
  const float* b_proj = (const float*)d_in[3];
  const float* a_raw = (const float*)d_in[4];
  const float* W_out = (const float*)d_in[5];
  const float* b_out = (const float*)d_in[6];
  const float* W_mu = (const float*)d_in[7];
  const float* b_mu = (const float*)d_in[8];
  const float* W_lv = (const float*)d_in[9];
  const float* b_lv = (const float*)d_in[10];
  float* out = (float*)d_out;

  // compact workspace (~8.6 MB)
  char* ws = (char*)d_ws;
  unsigned short* WT = (unsigned short*)ws;                       // 2 MB
  unsigned short* WoutT = (unsigned short*)(ws + 2097152);        // 2 MB
  unsigned short* WcatT = (unsigned short*)(ws + 4194304);        // 1 MB
  float* avec = (float*)(ws + 5242880);                           // 4 KB
  float* gvec = (float*)(ws + 5246976);                           // 4 KB
  float* a128v = (float*)(ws + 5251072);                          // 4 KB
  float* DredP = (float*)(ws + 5255168);                          // 2 MB
  unsigned short* hTbf = (unsigned short*)(ws + 7352320);         // 512 KB
  unsigned short* ybf = (unsigned short*)(ws + 7876608);          // 512 KB

  prep_kernel<<<1028, 256, 0, stream>>>(a_raw, W_proj, W_out, W_mu, W_lv,
                                        avec, gvec, a128v, WT, WoutT, WcatT);
  gemm_seg_kernel<<<4096, 256, 0, stream>>>(targets, decoder, WT, avec, gvec, b_proj, DredP);
  state_kernel<<<32, 256, 0, stream>>>(DredP, a128v, hTbf);
  head1_kernel<<<dim3(2, 8), 256, 0, stream>>>(hTbf, WoutT, b_out, ybf);
  head2_kernel<<<dim3(2, 4), 256, 0, stream>>>(ybf, WcatT, b_mu, b_lv, out);
}